// Round 4
// baseline (744.869 us; speedup 1.0000x reference)
//
#include <hip/hip_runtime.h>
#include <math.h>

#define NN 20000
#define EE 320000
#define FF 128
#define HH 256
#define HPITCH 264   // 256 + 8 bf16 pad
#define WPITCH 72    // 64 + 8 bf16 pad
#define TPITCH 130   // fp32 epilogue tile pitch
#define MT 64        // edges per block
#define NTHREADS 256
#define CH 79        // scan chunk: 256 blocks x 79 >= 20000

typedef __bf16 bf16x8 __attribute__((ext_vector_type(8)));
typedef float  f32x4  __attribute__((ext_vector_type(4)));

// ---- workspace layout (bytes) ----
#define CNT_OFF   0          // NN int32 (memset to 0)
#define BAR_OFF   80000      // 1 int32  (memset to 0)
#define WPTR_OFF  80016      // NN int32
#define PART_OFF  160016     // 256 int32
#define SSRC_OFF  161040     // EE u16
#define SDST_OFF  801040     // EE u16
#define XB_OFF    1441056    // NN*FF bf16
#define W1B_OFF   6561056    // HH*HH bf16
#define W2B_OFF   6692128    // HH*HH bf16
#define W3B_OFF   6823200    // FF*HH bf16  (end 6,888,736)

#define CVT_VEC ((NN*FF + HH*HH + HH*HH + FF*HH) / 4)   // 680,960 float4 groups
#define OUT_VEC (NN * FF / 4)                           // 640,000 float4
#define PREG    65536                                   // 256 blocks x 256 thr

__device__ __forceinline__ void gridbar(int* bar, int gen) {
    __syncthreads();
    if (threadIdx.x == 0) {
        __hip_atomic_fetch_add(bar, 1, __ATOMIC_ACQ_REL, __HIP_MEMORY_SCOPE_AGENT);
        const int target = 256 * (gen + 1);
        while (__hip_atomic_load(bar, __ATOMIC_ACQUIRE, __HIP_MEMORY_SCOPE_AGENT) < target)
            __builtin_amdgcn_s_sleep(1);
    }
    __syncthreads();
}

// persistent pre-pass: convert + zero-out + hist | bar | scanA | bar | scanB | bar | scatter
__global__ __launch_bounds__(256) void pre_kernel(
    const float* __restrict__ x,  const float* __restrict__ W1,
    const float* __restrict__ W2, const float* __restrict__ W3,
    const int*   __restrict__ eidx,
    __bf16* __restrict__ xb, __bf16* __restrict__ w1b,
    __bf16* __restrict__ w2b, __bf16* __restrict__ w3b,
    int* __restrict__ cnt, int* __restrict__ wptr, int* __restrict__ partials,
    unsigned short* __restrict__ ssrc, unsigned short* __restrict__ sdst,
    int* __restrict__ bar, float* __restrict__ outp)
{
    __shared__ int s_scan[256];
    const int t   = threadIdx.x;
    const int gid = blockIdx.x * 256 + t;

    // zero d_out
    float4* out4 = (float4*)outp;
    for (int i = gid; i < OUT_VEC; i += PREG) out4[i] = (float4){0.f, 0.f, 0.f, 0.f};
    // convert x,W1,W2,W3 -> bf16
    for (int i = gid; i < CVT_VEC; i += PREG) {
        const size_t base = (size_t)i * 4;
        const float* src; __bf16* dst; size_t off;
        if (base < (size_t)NN * FF)              { src = x;  dst = xb;  off = base; }
        else if (base < (size_t)NN*FF + HH*HH)   { src = W1; dst = w1b; off = base - (size_t)NN*FF; }
        else if (base < (size_t)NN*FF + 2*HH*HH) { src = W2; dst = w2b; off = base - (size_t)NN*FF - HH*HH; }
        else                                     { src = W3; dst = w3b; off = base - (size_t)NN*FF - 2*HH*HH; }
        float4 v = *(const float4*)(src + off);
        __bf16 o[4] = { (__bf16)v.x, (__bf16)v.y, (__bf16)v.z, (__bf16)v.w };
        __builtin_memcpy(dst + off, o, 8);
    }
    // histogram of dst (cnt pre-zeroed by memset)
    for (int e = gid; e < EE; e += PREG) atomicAdd(&cnt[eidx[EE + e]], 1);

    gridbar(bar, 0);

    // scan phase A: per-block exclusive scan of a CH-chunk of cnt
    {
        const int idx = blockIdx.x * CH + t;
        int v = (t < CH && idx < NN) ? cnt[idx] : 0;
        s_scan[t] = v;
        __syncthreads();
        for (int d = 1; d < 256; d <<= 1) {
            const int u = (t >= d) ? s_scan[t - d] : 0;
            __syncthreads();
            s_scan[t] += u;
            __syncthreads();
        }
        if (t < CH && idx < NN) wptr[idx] = s_scan[t] - v;   // local exclusive
        if (t == 255) partials[blockIdx.x] = s_scan[255];    // chunk total
    }

    gridbar(bar, 1);

    // scan phase B: block 0 exclusive-scans the 256 partials in place
    if (blockIdx.x == 0) {
        const int v = partials[t];
        s_scan[t] = v;
        __syncthreads();
        for (int d = 1; d < 256; d <<= 1) {
            const int u = (t >= d) ? s_scan[t - d] : 0;
            __syncthreads();
            s_scan[t] += u;
            __syncthreads();
        }
        partials[t] = s_scan[t] - v;
    }

    gridbar(bar, 2);

    // scatter: stable-ish counting-sort placement
    for (int e = gid; e < EE; e += PREG) {
        const int d = eidx[EE + e];
        const int pos = atomicAdd(&wptr[d], 1) + partials[d / CH];
        ssrc[pos] = (unsigned short)eidx[e];
        sdst[pos] = (unsigned short)d;
    }
}

__global__ __launch_bounds__(NTHREADS) void fused_edge_mlp(
    const __bf16* __restrict__ x,
    const unsigned short* __restrict__ ssrc,
    const unsigned short* __restrict__ sdst,
    const __bf16* __restrict__ W1,
    const float*  __restrict__ b1, const float* __restrict__ g1,
    const float*  __restrict__ be1, const float* __restrict__ rm1,
    const float*  __restrict__ rv1,
    const __bf16* __restrict__ W2,
    const float*  __restrict__ b2, const float* __restrict__ g2,
    const float*  __restrict__ be2, const float* __restrict__ rm2,
    const float*  __restrict__ rv2,
    const __bf16* __restrict__ W3,
    float* __restrict__ outp)
{
    __shared__ __align__(16) __bf16 sh_h[MT * HPITCH];   // 33792 B (reused as fp32 64x130 tile)
    __shared__ __align__(16) __bf16 sh_w[HH * WPITCH];   // 36864 B
    __shared__ float s_scale[2][HH];
    __shared__ float s_c[2][HH];
    __shared__ int   s_dst[MT];
    __shared__ int   s_src[MT];

    const int tid = threadIdx.x;
    const int e0  = blockIdx.x * MT;

    if (tid < MT) {
        s_src[tid] = (int)ssrc[e0 + tid];
        s_dst[tid] = (int)sdst[e0 + tid];
    }
    {   // BN constants (tid covers all 256 = HH)
        float sc1 = g1[tid] * rsqrtf(rv1[tid] + 1e-5f);
        s_scale[0][tid] = sc1;
        s_c[0][tid] = (b1[tid] - rm1[tid]) * sc1 + be1[tid];
        float sc2 = g2[tid] * rsqrtf(rv2[tid] + 1e-5f);
        s_scale[1][tid] = sc2;
        s_c[1][tid] = (b2[tid] - rm2[tid]) * sc2 + be2[tid];
    }
    __syncthreads();

    // ---- gather & concat: sh_h[r][0:128] = x[dst], sh_h[r][128:256] = x[src]-x[dst]
    {
        const int r = tid >> 2;       // 0..63
        const int q = tid & 3;        // 32-col quarter
        const __bf16* xd = x + (size_t)s_dst[r] * FF + q * 32;
        const __bf16* xs = x + (size_t)s_src[r] * FF + q * 32;
        uint4 di[4], sj[4];
        #pragma unroll
        for (int i = 0; i < 4; ++i) { di[i] = ((const uint4*)xd)[i]; sj[i] = ((const uint4*)xs)[i]; }
        __bf16* hrow = &sh_h[r * HPITCH];
        #pragma unroll
        for (int i = 0; i < 4; ++i) ((uint4*)&hrow[q * 32])[i] = di[i];
        #pragma unroll
        for (int i = 0; i < 4; ++i) {
            __bf16 a[8], b[8], ov[8];
            __builtin_memcpy(a, &di[i], 16);
            __builtin_memcpy(b, &sj[i], 16);
            #pragma unroll
            for (int j = 0; j < 8; ++j) ov[j] = (__bf16)((float)b[j] - (float)a[j]);
            uint4 o;
            __builtin_memcpy(&o, ov, 16);
            ((uint4*)&hrow[128 + q * 32])[i] = o;
        }
    }

    const int w    = tid >> 6;        // 4 waves
    const int lane = tid & 63;
    const int lr   = lane & 15;
    const int lq   = lane >> 4;

    // ---- stages 1 & 2: h = relu(scale * (h @ W^T) + c), in-place in sh_h
    #pragma unroll 1
    for (int stage = 0; stage < 2; ++stage) {
        const __bf16* Wp = (stage == 0) ? W1 : W2;
        const int n_base = w * 64;                    // wave owns 64 cols, all 64 rows
        f32x4 acc[4][4];
        #pragma unroll
        for (int i = 0; i < 4; ++i)
            #pragma unroll
            for (int j = 0; j < 4; ++j) acc[i][j] = (f32x4){0.f, 0.f, 0.f, 0.f};

        // register double-buffer: thread tid stages row n=tid, 64 k (128 B)
        const __bf16* wrow = Wp + (size_t)tid * HH;
        uint4 wreg[8];
        #pragma unroll
        for (int i = 0; i < 8; ++i) wreg[i] = ((const uint4*)wrow)[i];   // chunk 0

        #pragma unroll 1
        for (int kc = 0; kc < 4; ++kc) {
            __syncthreads();                         // prior MFMA reads of sh_w done
            {
                uint4* d4 = (uint4*)&sh_w[tid * WPITCH];
                #pragma unroll
                for (int i = 0; i < 8; ++i) d4[i] = wreg[i];
            }
            __syncthreads();                         // sh_w ready
            if (kc < 3) {                            // prefetch next chunk during MFMA
                const __bf16* p = wrow + (kc + 1) * 64;
                #pragma unroll
                for (int i = 0; i < 8; ++i) wreg[i] = ((const uint4*)p)[i];
            }
            #pragma unroll
            for (int kk = 0; kk < 2; ++kk) {
                bf16x8 af[4], bfr[4];
                #pragma unroll
                for (int i = 0; i < 4; ++i)
                    af[i] = *(const bf16x8*)&sh_h[(i * 16 + lr) * HPITCH + kc * 64 + kk * 32 + lq * 8];
                #pragma unroll
                for (int j = 0; j < 4; ++j)
                    bfr[j] = *(const bf16x8*)&sh_w[(n_base + j * 16 + lr) * WPITCH + kk * 32 + lq * 8];
                #pragma unroll
                for (int i = 0; i < 4; ++i)
                    #pragma unroll
                    for (int j = 0; j < 4; ++j)
                        acc[i][j] = __builtin_amdgcn_mfma_f32_16x16x32_bf16(af[i], bfr[j], acc[i][j], 0, 0, 0);
            }
        }
        __syncthreads();   // all reads of sh_h done -> safe to overwrite in place
        #pragma unroll
        for (int j = 0; j < 4; ++j) {
            const int n = n_base + j * 16 + lr;
            const float sc = s_scale[stage][n];
            const float cc = s_c[stage][n];
            #pragma unroll
            for (int i = 0; i < 4; ++i) {
                #pragma unroll
                for (int r = 0; r < 4; ++r) {
                    const int m = i * 16 + lq * 4 + r;
                    float v = acc[i][j][r] * sc + cc;
                    sh_h[m * HPITCH + n] = (__bf16)fmaxf(v, 0.0f);
                }
            }
        }
    }

    // ---- stage 3: [64x256] @ W3^T -> [64x128], LDS tile, segmented scatter-add
    {
        const int wm = w >> 1, wn = w & 1;          // 2 x 2 wave grid
        const int m_base = wm * 32, n_base = wn * 64;
        f32x4 acc[2][4];
        #pragma unroll
        for (int i = 0; i < 2; ++i)
            #pragma unroll
            for (int j = 0; j < 4; ++j) acc[i][j] = (f32x4){0.f, 0.f, 0.f, 0.f};

        // register double-buffer: thread stages row n=tid>>1, half=tid&1 (64 B)
        const __bf16* w3row = W3 + (size_t)(tid >> 1) * HH + (tid & 1) * 32;
        uint4 w3reg[4];
        #pragma unroll
        for (int i = 0; i < 4; ++i) w3reg[i] = ((const uint4*)w3row)[i];

        #pragma unroll 1
        for (int kc = 0; kc < 4; ++kc) {
            __syncthreads();
            {
                uint4* d4 = (uint4*)&sh_w[(tid >> 1) * WPITCH + (tid & 1) * 32];
                #pragma unroll
                for (int i = 0; i < 4; ++i) d4[i] = w3reg[i];
            }
            __syncthreads();
            if (kc < 3) {
                const __bf16* p = w3row + (kc + 1) * 64;
                #pragma unroll
                for (int i = 0; i < 4; ++i) w3reg[i] = ((const uint4*)p)[i];
            }
            #pragma unroll
            for (int kk = 0; kk < 2; ++kk) {
                bf16x8 af[2], bfr[4];
                #pragma unroll
                for (int i = 0; i < 2; ++i)
                    af[i] = *(const bf16x8*)&sh_h[(m_base + i * 16 + lr) * HPITCH + kc * 64 + kk * 32 + lq * 8];
                #pragma unroll
                for (int j = 0; j < 4; ++j)
                    bfr[j] = *(const bf16x8*)&sh_w[(n_base + j * 16 + lr) * WPITCH + kk * 32 + lq * 8];
                #pragma unroll
                for (int i = 0; i < 2; ++i)
                    #pragma unroll
                    for (int j = 0; j < 4; ++j)
                        acc[i][j] = __builtin_amdgcn_mfma_f32_16x16x32_bf16(af[i], bfr[j], acc[i][j], 0, 0, 0);
            }
        }

        __syncthreads();   // K-loop reads of sh_h complete before reuse as fp32 tile
        float* tile = (float*)sh_h;   // 64 x TPITCH fp32 (33280 B <= 33792 B)
        #pragma unroll
        for (int j = 0; j < 4; ++j) {
            const int n = n_base + j * 16 + lr;
            #pragma unroll
            for (int i = 0; i < 2; ++i) {
                #pragma unroll
                for (int r = 0; r < 4; ++r)
                    tile[(m_base + i * 16 + lq * 4 + r) * TPITCH + n] = acc[i][j][r];
            }
        }
        __syncthreads();

        // segmented reduction: sorted dst -> ~1 atomic per segment per col
        {
            const int col = tid & 127;
            const int r0  = (tid >> 7) * 32;       // 2 chunks of 32 rows
            int cur = s_dst[r0];
            float run = 0.f;
            #pragma unroll 1
            for (int r = r0; r < r0 + 32; ++r) {
                const int d = s_dst[r];            // wave-uniform
                if (d != cur) {
                    atomicAdd(&outp[(size_t)cur * FF + col], run);
                    run = 0.f; cur = d;
                }
                run += tile[r * TPITCH + col];
            }
            atomicAdd(&outp[(size_t)cur * FF + col], run);
        }
    }
}

__global__ __launch_bounds__(256) void finalize_kernel(const int* __restrict__ cnt,
                                                       const float* __restrict__ b3,
                                                       float* __restrict__ out)
{
    const int i4 = blockIdx.x * 256 + threadIdx.x;
    if (i4 < OUT_VEC) {
        const int node = i4 >> 5;               // 32 float4 per row
        const int cb   = (i4 & 31) * 4;
        const float c = fmaxf((float)cnt[node], 1.0f);
        float4 v = ((float4*)out)[i4];
        v.x = tanhf(v.x / c + b3[cb + 0]);
        v.y = tanhf(v.y / c + b3[cb + 1]);
        v.z = tanhf(v.z / c + b3[cb + 2]);
        v.w = tanhf(v.w / c + b3[cb + 3]);
        ((float4*)out)[i4] = v;
    }
}

extern "C" void kernel_launch(void* const* d_in, const int* in_sizes, int n_in,
                              void* d_out, int out_size, void* d_ws, size_t ws_size,
                              hipStream_t stream)
{
    const float* x   = (const float*)d_in[0];
    const int*   ei  = (const int*)d_in[1];
    const float* W1  = (const float*)d_in[2];
    const float* b1  = (const float*)d_in[3];
    const float* g1  = (const float*)d_in[4];
    const float* be1 = (const float*)d_in[5];
    const float* rm1 = (const float*)d_in[6];
    const float* rv1 = (const float*)d_in[7];
    const float* W2  = (const float*)d_in[8];
    const float* b2  = (const float*)d_in[9];
    const float* g2  = (const float*)d_in[10];
    const float* be2 = (const float*)d_in[11];
    const float* rm2 = (const float*)d_in[12];
    const float* rv2 = (const float*)d_in[13];
    const float* W3  = (const float*)d_in[14];
    const float* b3  = (const float*)d_in[15];

    char* ws = (char*)d_ws;
    int* cnt_i = (int*)(ws + CNT_OFF);
    int* bar   = (int*)(ws + BAR_OFF);
    int* wptr  = (int*)(ws + WPTR_OFF);
    int* part  = (int*)(ws + PART_OFF);
    unsigned short* ssrc = (unsigned short*)(ws + SSRC_OFF);
    unsigned short* sdst = (unsigned short*)(ws + SDST_OFF);
    __bf16* xb  = (__bf16*)(ws + XB_OFF);
    __bf16* w1b = (__bf16*)(ws + W1B_OFF);
    __bf16* w2b = (__bf16*)(ws + W2B_OFF);
    __bf16* w3b = (__bf16*)(ws + W3B_OFF);
    float* outp = (float*)d_out;

    hipMemsetAsync(ws, 0, BAR_OFF + 4, stream);   // zero cnt + grid barrier

    pre_kernel<<<256, 256, 0, stream>>>(x, W1, W2, W3, ei,
                                        xb, w1b, w2b, w3b,
                                        cnt_i, wptr, part, ssrc, sdst, bar, outp);
    fused_edge_mlp<<<EE / MT, NTHREADS, 0, stream>>>(xb, ssrc, sdst,
                                                     w1b, b1, g1, be1, rm1, rv1,
                                                     w2b, b2, g2, be2, rm2, rv2,
                                                     w3b, outp);
    finalize_kernel<<<(OUT_VEC + 255) / 256, 256, 0, stream>>>(cnt_i, b3, outp);
}

// Round 6
// 425.780 us; speedup vs baseline: 1.7494x; 1.7494x over previous
//
#include <hip/hip_runtime.h>
#include <math.h>

#define NN 20000
#define EE 320000
#define FF 128
#define HH 256
#define HPITCH 264   // 256 + 8 bf16 pad
#define WPITCH 72    // 64 + 8 bf16 pad
#define TPITCH 130   // fp32 epilogue tile pitch
#define MT 128       // edges per block
#define NTHREADS 512

typedef __bf16 bf16x8 __attribute__((ext_vector_type(8)));
typedef float  f32x4  __attribute__((ext_vector_type(4)));

// ---- workspace layout (bytes) ----
#define CNT_OFF   0          // NN int32 (memset to 0)
#define WPTR_OFF  80000      // NN int32
#define SSRC_OFF  160000     // EE u16
#define SDST_OFF  800000     // EE u16
#define XB_OFF    1440000    // NN*FF bf16
#define W1B_OFF   6560000    // HH*HH bf16
#define W2B_OFF   6691072    // HH*HH bf16
#define W3B_OFF   6822144    // FF*HH bf16  (end 6,887,680)

#define CVT_VEC ((NN*FF + HH*HH + HH*HH + FF*HH) / 4)   // 680,960 float4 groups
#define OUT_VEC (NN * FF / 4)                           // 640,000 float4

// zero d_out + convert x/W1/W2/W3 to bf16 + dst histogram, one dispatch
__global__ __launch_bounds__(256) void prep_kernel(
    const float* __restrict__ x,  const float* __restrict__ W1,
    const float* __restrict__ W2, const float* __restrict__ W3,
    const int*   __restrict__ eidx,
    __bf16* __restrict__ xb, __bf16* __restrict__ w1b,
    __bf16* __restrict__ w2b, __bf16* __restrict__ w3b,
    int* __restrict__ cnt, float* __restrict__ outp)
{
    const int gid = blockIdx.x * 256 + threadIdx.x;
    if (gid < OUT_VEC) ((float4*)outp)[gid] = (float4){0.f, 0.f, 0.f, 0.f};
    if (gid < CVT_VEC) {
        const size_t base = (size_t)gid * 4;
        const float* src; __bf16* dst; size_t off;
        if (base < (size_t)NN * FF)              { src = x;  dst = xb;  off = base; }
        else if (base < (size_t)NN*FF + HH*HH)   { src = W1; dst = w1b; off = base - (size_t)NN*FF; }
        else if (base < (size_t)NN*FF + 2*HH*HH) { src = W2; dst = w2b; off = base - (size_t)NN*FF - HH*HH; }
        else                                     { src = W3; dst = w3b; off = base - (size_t)NN*FF - 2*HH*HH; }
        float4 v = *(const float4*)(src + off);
        __bf16 o[4] = { (__bf16)v.x, (__bf16)v.y, (__bf16)v.z, (__bf16)v.w };
        __builtin_memcpy(dst + off, o, 8);
    }
    if (gid < EE) atomicAdd(&cnt[eidx[EE + gid]], 1);
}

// exclusive prefix sum of cnt[0..NN) -> wptr, single block of 1024 threads
__global__ __launch_bounds__(1024) void scan_kernel(const int* __restrict__ cnt,
                                                    int* __restrict__ wptr)
{
    __shared__ int s_part[1024];
    const int t = threadIdx.x;
    const int base = t * 20;
    int loc[20];
    int sum = 0;
    #pragma unroll
    for (int i = 0; i < 20; ++i) {
        const int idx = base + i;
        const int v = (idx < NN) ? cnt[idx] : 0;
        loc[i] = sum;
        sum += v;
    }
    s_part[t] = sum;
    __syncthreads();
    for (int d = 1; d < 1024; d <<= 1) {
        const int v = (t >= d) ? s_part[t - d] : 0;
        __syncthreads();
        s_part[t] += v;
        __syncthreads();
    }
    const int excl = s_part[t] - sum;
    #pragma unroll
    for (int i = 0; i < 20; ++i) {
        const int idx = base + i;
        if (idx < NN) wptr[idx] = excl + loc[i];
    }
}

__global__ __launch_bounds__(256) void scatter_kernel(const int* __restrict__ eidx,
                                                      int* __restrict__ wptr,
                                                      unsigned short* __restrict__ ssrc,
                                                      unsigned short* __restrict__ sdst)
{
    const int e = blockIdx.x * 256 + threadIdx.x;
    if (e < EE) {
        const int d = eidx[EE + e];
        const int pos = atomicAdd(&wptr[d], 1);
        ssrc[pos] = (unsigned short)eidx[e];
        sdst[pos] = (unsigned short)d;
    }
}

__global__ __launch_bounds__(NTHREADS) void fused_edge_mlp(
    const __bf16* __restrict__ x,
    const unsigned short* __restrict__ ssrc,
    const unsigned short* __restrict__ sdst,
    const __bf16* __restrict__ W1,
    const float*  __restrict__ b1, const float* __restrict__ g1,
    const float*  __restrict__ be1, const float* __restrict__ rm1,
    const float*  __restrict__ rv1,
    const __bf16* __restrict__ W2,
    const float*  __restrict__ b2, const float* __restrict__ g2,
    const float*  __restrict__ be2, const float* __restrict__ rm2,
    const float*  __restrict__ rv2,
    const __bf16* __restrict__ W3,
    float* __restrict__ outp)
{
    __shared__ __align__(16) __bf16 sh_h[MT * HPITCH];   // 67584 B (reused as fp32 128x130 tile)
    __shared__ __align__(16) __bf16 sh_w[HH * WPITCH];   // 36864 B
    __shared__ float s_scale[2][HH];
    __shared__ float s_c[2][HH];
    __shared__ int   s_dst[MT];
    __shared__ int   s_src[MT];

    const int tid = threadIdx.x;
    const int e0  = blockIdx.x * MT;

    if (tid < MT) {
        s_src[tid] = (int)ssrc[e0 + tid];
        s_dst[tid] = (int)sdst[e0 + tid];
    }
    if (tid < HH) {
        float sc1 = g1[tid] * rsqrtf(rv1[tid] + 1e-5f);
        s_scale[0][tid] = sc1;
        s_c[0][tid] = (b1[tid] - rm1[tid]) * sc1 + be1[tid];
        float sc2 = g2[tid] * rsqrtf(rv2[tid] + 1e-5f);
        s_scale[1][tid] = sc2;
        s_c[1][tid] = (b2[tid] - rm2[tid]) * sc2 + be2[tid];
    }
    __syncthreads();

    // ---- gather & concat: sh_h[r][0:128] = x[dst], sh_h[r][128:256] = x[src]-x[dst]
    {
        const int r = tid >> 2;       // 0..127
        const int q = tid & 3;        // 32-col quarter
        const __bf16* xd = x + (size_t)s_dst[r] * FF + q * 32;
        const __bf16* xs = x + (size_t)s_src[r] * FF + q * 32;
        uint4 di[4], sj[4];
        #pragma unroll
        for (int i = 0; i < 4; ++i) { di[i] = ((const uint4*)xd)[i]; sj[i] = ((const uint4*)xs)[i]; }
        __bf16* hrow = &sh_h[r * HPITCH];
        #pragma unroll
        for (int i = 0; i < 4; ++i) ((uint4*)&hrow[q * 32])[i] = di[i];
        #pragma unroll
        for (int i = 0; i < 4; ++i) {
            __bf16 a[8], b[8], ov[8];
            __builtin_memcpy(a, &di[i], 16);
            __builtin_memcpy(b, &sj[i], 16);
            #pragma unroll
            for (int j = 0; j < 8; ++j) ov[j] = (__bf16)((float)b[j] - (float)a[j]);
            uint4 o;
            __builtin_memcpy(&o, ov, 16);
            ((uint4*)&hrow[128 + q * 32])[i] = o;
        }
    }

    const int w    = tid >> 6;
    const int lane = tid & 63;
    const int lr   = lane & 15;
    const int lq   = lane >> 4;

    // ---- stages 1 & 2: h = relu(scale * (h @ W^T) + c), in-place in sh_h
    #pragma unroll 1
    for (int stage = 0; stage < 2; ++stage) {
        const __bf16* Wp = (stage == 0) ? W1 : W2;
        const int wm = w >> 2, wn = w & 3;          // 2 x 4 wave grid
        const int m_base = wm * 64, n_base = wn * 64;
        f32x4 acc[4][4];
        #pragma unroll
        for (int i = 0; i < 4; ++i)
            #pragma unroll
            for (int j = 0; j < 4; ++j) acc[i][j] = (f32x4){0.f, 0.f, 0.f, 0.f};

        // staging: thread owns 64 B of the [256 n][64 k] chunk: row tid>>1, half (tid&1)*32
        const __bf16* wrow = Wp + (size_t)(tid >> 1) * HH + (tid & 1) * 32;
        uint4 wreg[4];
        #pragma unroll
        for (int i = 0; i < 4; ++i) wreg[i] = ((const uint4*)wrow)[i];   // chunk 0 prefetch

        #pragma unroll 1
        for (int kc = 0; kc < 4; ++kc) {
            __syncthreads();                         // prior MFMA reads of sh_w done
            {
                uint4* d4 = (uint4*)&sh_w[(tid >> 1) * WPITCH + (tid & 1) * 32];
                #pragma unroll
                for (int i = 0; i < 4; ++i) d4[i] = wreg[i];
            }
            __syncthreads();                         // sh_w ready
            if (kc < 3) {                            // prefetch next chunk under MFMA
                const __bf16* p = wrow + (kc + 1) * 64;
                #pragma unroll
                for (int i = 0; i < 4; ++i) wreg[i] = ((const uint4*)p)[i];
            }
            #pragma unroll
            for (int kk = 0; kk < 2; ++kk) {
                bf16x8 af[4], bfr[4];
                #pragma unroll
                for (int i = 0; i < 4; ++i)
                    af[i] = *(const bf16x8*)&sh_h[(m_base + i * 16 + lr) * HPITCH + kc * 64 + kk * 32 + lq * 8];
                #pragma unroll
                for (int j = 0; j < 4; ++j)
                    bfr[j] = *(const bf16x8*)&sh_w[(n_base + j * 16 + lr) * WPITCH + kk * 32 + lq * 8];
                #pragma unroll
                for (int i = 0; i < 4; ++i)
                    #pragma unroll
                    for (int j = 0; j < 4; ++j)
                        acc[i][j] = __builtin_amdgcn_mfma_f32_16x16x32_bf16(af[i], bfr[j], acc[i][j], 0, 0, 0);
            }
        }
        __syncthreads();   // all reads of sh_h done -> safe to overwrite in place
        #pragma unroll
        for (int j = 0; j < 4; ++j) {
            const int n = n_base + j * 16 + lr;
            const float sc = s_scale[stage][n];
            const float cc = s_c[stage][n];
            #pragma unroll
            for (int i = 0; i < 4; ++i) {
                #pragma unroll
                for (int r = 0; r < 4; ++r) {
                    const int m = m_base + i * 16 + lq * 4 + r;
                    float v = acc[i][j][r] * sc + cc;
                    sh_h[m * HPITCH + n] = (__bf16)fmaxf(v, 0.0f);
                }
            }
        }
    }

    // ---- stage 3: [128x256] @ W3^T -> [128x128], LDS tile, segmented scatter-add
    {
        const int wm = w >> 1, wn = w & 1;          // 4 x 2 wave grid
        const int m_base = wm * 32, n_base = wn * 64;
        f32x4 acc[2][4];
        #pragma unroll
        for (int i = 0; i < 2; ++i)
            #pragma unroll
            for (int j = 0; j < 4; ++j) acc[i][j] = (f32x4){0.f, 0.f, 0.f, 0.f};

        // staging (tid<256): thread owns 64 B of [128 n][64 k]: row tid>>1, half (tid&1)*32
        const __bf16* w3row = W3 + (size_t)(tid >> 1) * HH + (tid & 1) * 32;
        uint4 w3reg[4];
        if (tid < 256) {
            #pragma unroll
            for (int i = 0; i < 4; ++i) w3reg[i] = ((const uint4*)w3row)[i];
        }

        #pragma unroll 1
        for (int kc = 0; kc < 4; ++kc) {
            __syncthreads();
            if (tid < 256) {
                uint4* d4 = (uint4*)&sh_w[(tid >> 1) * WPITCH + (tid & 1) * 32];
                #pragma unroll
                for (int i = 0; i < 4; ++i) d4[i] = w3reg[i];
            }
            __syncthreads();
            if (tid < 256 && kc < 3) {
                const __bf16* p = w3row + (kc + 1) * 64;
                #pragma unroll
                for (int i = 0; i < 4; ++i) w3reg[i] = ((const uint4*)p)[i];
            }
            #pragma unroll
            for (int kk = 0; kk < 2; ++kk) {
                bf16x8 af[2], bfr[4];
                #pragma unroll
                for (int i = 0; i < 2; ++i)
                    af[i] = *(const bf16x8*)&sh_h[(m_base + i * 16 + lr) * HPITCH + kc * 64 + kk * 32 + lq * 8];
                #pragma unroll
                for (int j = 0; j < 4; ++j)
                    bfr[j] = *(const bf16x8*)&sh_w[(n_base + j * 16 + lr) * WPITCH + kk * 32 + lq * 8];
                #pragma unroll
                for (int i = 0; i < 2; ++i)
                    #pragma unroll
                    for (int j = 0; j < 4; ++j)
                        acc[i][j] = __builtin_amdgcn_mfma_f32_16x16x32_bf16(af[i], bfr[j], acc[i][j], 0, 0, 0);
            }
        }

        __syncthreads();   // K-loop reads of sh_h complete before reuse as fp32 tile
        float* tile = (float*)sh_h;   // 128 x TPITCH fp32 (66560 B <= 67584 B)
        #pragma unroll
        for (int j = 0; j < 4; ++j) {
            const int n = n_base + j * 16 + lr;
            #pragma unroll
            for (int i = 0; i < 2; ++i) {
                #pragma unroll
                for (int r = 0; r < 4; ++r)
                    tile[(m_base + i * 16 + lq * 4 + r) * TPITCH + n] = acc[i][j][r];
            }
        }
        __syncthreads();

        // segmented reduction: sorted dst -> ~1 atomic per segment per col
        {
            const int col = tid & 127;
            const int r0  = (tid >> 7) * 32;       // 4 chunks of 32 rows
            int cur = s_dst[r0];
            float run = 0.f;
            #pragma unroll 1
            for (int r = r0; r < r0 + 32; ++r) {
                const int d = s_dst[r];            // wave-uniform
                if (d != cur) {
                    atomicAdd(&outp[(size_t)cur * FF + col], run);
                    run = 0.f; cur = d;
                }
                run += tile[r * TPITCH + col];
            }
            atomicAdd(&outp[(size_t)cur * FF + col], run);
        }
    }
}

__global__ __launch_bounds__(256) void finalize_kernel(const int* __restrict__ cnt,
                                                       const float* __restrict__ b3,
                                                       float* __restrict__ out)
{
    const int i4 = blockIdx.x * 256 + threadIdx.x;
    if (i4 < OUT_VEC) {
        const int node = i4 >> 5;               // 32 float4 per row
        const int cb   = (i4 & 31) * 4;
        const int c_i  = cnt[node];
        float4 v = ((float4*)out)[i4];
        if (c_i > 0) {
            const float inv = 1.0f / (float)c_i;
            v.x = tanhf(v.x * inv + b3[cb + 0]);
            v.y = tanhf(v.y * inv + b3[cb + 1]);
            v.z = tanhf(v.z * inv + b3[cb + 2]);
            v.w = tanhf(v.w * inv + b3[cb + 3]);
        } else {
            v = (float4){0.f, 0.f, 0.f, 0.f};   // reference: tanh(0/1) = 0
        }
        ((float4*)out)[i4] = v;
    }
}

extern "C" void kernel_launch(void* const* d_in, const int* in_sizes, int n_in,
                              void* d_out, int out_size, void* d_ws, size_t ws_size,
                              hipStream_t stream)
{
    const float* x   = (const float*)d_in[0];
    const int*   ei  = (const int*)d_in[1];
    const float* W1  = (const float*)d_in[2];
    const float* b1  = (const float*)d_in[3];
    const float* g1  = (const float*)d_in[4];
    const float* be1 = (const float*)d_in[5];
    const float* rm1 = (const float*)d_in[6];
    const float* rv1 = (const float*)d_in[7];
    const float* W2  = (const float*)d_in[8];
    const float* b2  = (const float*)d_in[9];
    const float* g2  = (const float*)d_in[10];
    const float* be2 = (const float*)d_in[11];
    const float* rm2 = (const float*)d_in[12];
    const float* rv2 = (const float*)d_in[13];
    const float* W3  = (const float*)d_in[14];
    const float* b3  = (const float*)d_in[15];

    char* ws = (char*)d_ws;
    int* cnt_i = (int*)(ws + CNT_OFF);
    int* wptr  = (int*)(ws + WPTR_OFF);
    unsigned short* ssrc = (unsigned short*)(ws + SSRC_OFF);
    unsigned short* sdst = (unsigned short*)(ws + SDST_OFF);
    __bf16* xb  = (__bf16*)(ws + XB_OFF);
    __bf16* w1b = (__bf16*)(ws + W1B_OFF);
    __bf16* w2b = (__bf16*)(ws + W2B_OFF);
    __bf16* w3b = (__bf16*)(ws + W3B_OFF);
    float* outp = (float*)d_out;

    hipMemsetAsync(cnt_i, 0, NN * sizeof(int), stream);
    prep_kernel<<<(CVT_VEC + 255) / 256, 256, 0, stream>>>(x, W1, W2, W3, ei,
                                                           xb, w1b, w2b, w3b,
                                                           cnt_i, outp);
    scan_kernel<<<1, 1024, 0, stream>>>(cnt_i, wptr);
    scatter_kernel<<<(EE + 255) / 256, 256, 0, stream>>>(ei, wptr, ssrc, sdst);
    fused_edge_mlp<<<EE / MT, NTHREADS, 0, stream>>>(xb, ssrc, sdst,
                                                     w1b, b1, g1, be1, rm1, rv1,
                                                     w2b, b2, g2, be2, rm2, rv2,
                                                     w3b, outp);
    finalize_kernel<<<(OUT_VEC + 255) / 256, 256, 0, stream>>>(cnt_i, b3, outp);
}

// Round 7
// 391.733 us; speedup vs baseline: 1.9015x; 1.0869x over previous
//
#include <hip/hip_runtime.h>
#include <math.h>

#define NN 20000
#define EE 320000
#define FF 128
#define HH 256
#define HPITCH 264   // 256 + 8 bf16 pad
#define TPITCH 130   // fp32 epilogue tile pitch
#define MT 128       // edges per block
#define NTHREADS 512

typedef __bf16 bf16x8 __attribute__((ext_vector_type(8)));
typedef float  f32x4  __attribute__((ext_vector_type(4)));

// ---- workspace layout (bytes) ----
#define CNT_OFF   0          // NN int32 (memset to 0)
#define WPTR_OFF  80000      // NN int32
#define SSRC_OFF  160000     // EE u16
#define SDST_OFF  800000     // EE u16
#define XB_OFF    1440000    // NN*FF bf16
#define W1B_OFF   6560000    // HH*HH bf16
#define W2B_OFF   6691072    // HH*HH bf16
#define W3B_OFF   6822144    // FF*HH bf16  (end 6,887,680)

#define CVT_VEC ((NN*FF + HH*HH + HH*HH + FF*HH) / 4)   // 680,960 float4 groups
#define OUT_VEC (NN * FF / 4)                           // 640,000 float4

// zero d_out + convert x/W1/W2/W3 to bf16 + dst histogram, one dispatch
__global__ __launch_bounds__(256) void prep_kernel(
    const float* __restrict__ x,  const float* __restrict__ W1,
    const float* __restrict__ W2, const float* __restrict__ W3,
    const int*   __restrict__ eidx,
    __bf16* __restrict__ xb, __bf16* __restrict__ w1b,
    __bf16* __restrict__ w2b, __bf16* __restrict__ w3b,
    int* __restrict__ cnt, float* __restrict__ outp)
{
    const int gid = blockIdx.x * 256 + threadIdx.x;
    if (gid < OUT_VEC) ((float4*)outp)[gid] = (float4){0.f, 0.f, 0.f, 0.f};
    if (gid < CVT_VEC) {
        const size_t base = (size_t)gid * 4;
        const float* src; __bf16* dst; size_t off;
        if (base < (size_t)NN * FF)              { src = x;  dst = xb;  off = base; }
        else if (base < (size_t)NN*FF + HH*HH)   { src = W1; dst = w1b; off = base - (size_t)NN*FF; }
        else if (base < (size_t)NN*FF + 2*HH*HH) { src = W2; dst = w2b; off = base - (size_t)NN*FF - HH*HH; }
        else                                     { src = W3; dst = w3b; off = base - (size_t)NN*FF - 2*HH*HH; }
        float4 v = *(const float4*)(src + off);
        __bf16 o[4] = { (__bf16)v.x, (__bf16)v.y, (__bf16)v.z, (__bf16)v.w };
        __builtin_memcpy(dst + off, o, 8);
    }
    if (gid < EE) atomicAdd(&cnt[eidx[EE + gid]], 1);
}

// exclusive prefix sum of cnt[0..NN) -> wptr, single block of 1024 threads
__global__ __launch_bounds__(1024) void scan_kernel(const int* __restrict__ cnt,
                                                    int* __restrict__ wptr)
{
    __shared__ int s_part[1024];
    const int t = threadIdx.x;
    const int base = t * 20;
    int loc[20];
    int sum = 0;
    #pragma unroll
    for (int i = 0; i < 20; ++i) {
        const int idx = base + i;
        const int v = (idx < NN) ? cnt[idx] : 0;
        loc[i] = sum;
        sum += v;
    }
    s_part[t] = sum;
    __syncthreads();
    for (int d = 1; d < 1024; d <<= 1) {
        const int v = (t >= d) ? s_part[t - d] : 0;
        __syncthreads();
        s_part[t] += v;
        __syncthreads();
    }
    const int excl = s_part[t] - sum;
    #pragma unroll
    for (int i = 0; i < 20; ++i) {
        const int idx = base + i;
        if (idx < NN) wptr[idx] = excl + loc[i];
    }
}

__global__ __launch_bounds__(256) void scatter_kernel(const int* __restrict__ eidx,
                                                      int* __restrict__ wptr,
                                                      unsigned short* __restrict__ ssrc,
                                                      unsigned short* __restrict__ sdst)
{
    const int e = blockIdx.x * 256 + threadIdx.x;
    if (e < EE) {
        const int d = eidx[EE + e];
        const int pos = atomicAdd(&wptr[d], 1);
        ssrc[pos] = (unsigned short)eidx[e];
        sdst[pos] = (unsigned short)d;
    }
}

__global__ __launch_bounds__(NTHREADS, 4) void fused_edge_mlp(
    const __bf16* __restrict__ x,
    const unsigned short* __restrict__ ssrc,
    const unsigned short* __restrict__ sdst,
    const __bf16* __restrict__ W1,
    const float*  __restrict__ b1, const float* __restrict__ g1,
    const float*  __restrict__ be1, const float* __restrict__ rm1,
    const float*  __restrict__ rv1,
    const __bf16* __restrict__ W2,
    const float*  __restrict__ b2, const float* __restrict__ g2,
    const float*  __restrict__ be2, const float* __restrict__ rm2,
    const float*  __restrict__ rv2,
    const __bf16* __restrict__ W3,
    float* __restrict__ outp)
{
    __shared__ __align__(16) __bf16 sh_h[MT * HPITCH];   // 67584 B (reused as fp32 128x130 tile)
    __shared__ float s_scale[2][HH];
    __shared__ float s_c[2][HH];
    __shared__ int   s_dst[MT];
    __shared__ int   s_src[MT];
    // total 72704 B -> 2 blocks/CU

    const int tid = threadIdx.x;
    const int e0  = blockIdx.x * MT;

    if (tid < MT) {
        s_src[tid] = (int)ssrc[e0 + tid];
        s_dst[tid] = (int)sdst[e0 + tid];
    }
    if (tid < HH) {
        float sc1 = g1[tid] * rsqrtf(rv1[tid] + 1e-5f);
        s_scale[0][tid] = sc1;
        s_c[0][tid] = (b1[tid] - rm1[tid]) * sc1 + be1[tid];
        float sc2 = g2[tid] * rsqrtf(rv2[tid] + 1e-5f);
        s_scale[1][tid] = sc2;
        s_c[1][tid] = (b2[tid] - rm2[tid]) * sc2 + be2[tid];
    }
    __syncthreads();

    // ---- gather & concat: sh_h[r][0:128] = x[dst], sh_h[r][128:256] = x[src]-x[dst]
    {
        const int r = tid >> 2;       // 0..127
        const int q = tid & 3;        // 32-col quarter
        const __bf16* xd = x + (size_t)s_dst[r] * FF + q * 32;
        const __bf16* xs = x + (size_t)s_src[r] * FF + q * 32;
        uint4 di[4], sj[4];
        #pragma unroll
        for (int i = 0; i < 4; ++i) { di[i] = ((const uint4*)xd)[i]; sj[i] = ((const uint4*)xs)[i]; }
        __bf16* hrow = &sh_h[r * HPITCH];
        #pragma unroll
        for (int i = 0; i < 4; ++i) ((uint4*)&hrow[q * 32])[i] = di[i];
        #pragma unroll
        for (int i = 0; i < 4; ++i) {
            __bf16 a[8], b[8], ov[8];
            __builtin_memcpy(a, &di[i], 16);
            __builtin_memcpy(b, &sj[i], 16);
            #pragma unroll
            for (int j = 0; j < 8; ++j) ov[j] = (__bf16)((float)b[j] - (float)a[j]);
            uint4 o;
            __builtin_memcpy(&o, ov, 16);
            ((uint4*)&hrow[128 + q * 32])[i] = o;
        }
    }
    __syncthreads();

    const int w    = tid >> 6;
    const int lane = tid & 63;
    const int lr   = lane & 15;
    const int lq   = lane >> 4;

    // ---- stages 1 & 2: h = relu(scale * (h @ W^T) + c), in-place in sh_h
    // B-fragments come straight from global (L2-resident weights) -> no K-loop barriers.
    #pragma unroll 1
    for (int stage = 0; stage < 2; ++stage) {
        const __bf16* Wp = (stage == 0) ? W1 : W2;
        const int wm = w >> 2, wn = w & 3;          // 2 x 4 wave grid
        const int m_base = wm * 64, n_base = wn * 64;
        const __bf16* wbase = Wp + (size_t)(n_base + lr) * HH + lq * 8;
        f32x4 acc[4][4];
        #pragma unroll
        for (int i = 0; i < 4; ++i)
            #pragma unroll
            for (int j = 0; j < 4; ++j) acc[i][j] = (f32x4){0.f, 0.f, 0.f, 0.f};

        #pragma unroll
        for (int ks = 0; ks < 8; ++ks) {            // K = 8 x 32
            bf16x8 af[4], bfr[4];
            #pragma unroll
            for (int i = 0; i < 4; ++i)
                af[i] = *(const bf16x8*)&sh_h[(m_base + i * 16 + lr) * HPITCH + ks * 32 + lq * 8];
            #pragma unroll
            for (int j = 0; j < 4; ++j)
                bfr[j] = *(const bf16x8*)(wbase + (size_t)j * 16 * HH + ks * 32);
            #pragma unroll
            for (int i = 0; i < 4; ++i)
                #pragma unroll
                for (int j = 0; j < 4; ++j)
                    acc[i][j] = __builtin_amdgcn_mfma_f32_16x16x32_bf16(af[i], bfr[j], acc[i][j], 0, 0, 0);
        }
        __syncthreads();   // all reads of sh_h done -> safe to overwrite in place
        #pragma unroll
        for (int j = 0; j < 4; ++j) {
            const int n = n_base + j * 16 + lr;
            const float sc = s_scale[stage][n];
            const float cc = s_c[stage][n];
            #pragma unroll
            for (int i = 0; i < 4; ++i) {
                #pragma unroll
                for (int r = 0; r < 4; ++r) {
                    const int m = m_base + i * 16 + lq * 4 + r;
                    float v = acc[i][j][r] * sc + cc;
                    sh_h[m * HPITCH + n] = (__bf16)fmaxf(v, 0.0f);
                }
            }
        }
        __syncthreads();   // writes visible before next stage reads
    }

    // ---- stage 3: [128x256] @ W3^T -> [128x128], LDS tile, segmented scatter-add
    {
        const int wm = w >> 1, wn = w & 1;          // 4 x 2 wave grid
        const int m_base = wm * 32, n_base = wn * 64;
        const __bf16* wbase = W3 + (size_t)(n_base + lr) * HH + lq * 8;
        f32x4 acc[2][4];
        #pragma unroll
        for (int i = 0; i < 2; ++i)
            #pragma unroll
            for (int j = 0; j < 4; ++j) acc[i][j] = (f32x4){0.f, 0.f, 0.f, 0.f};

        #pragma unroll
        for (int ks = 0; ks < 8; ++ks) {
            bf16x8 af[2], bfr[4];
            #pragma unroll
            for (int i = 0; i < 2; ++i)
                af[i] = *(const bf16x8*)&sh_h[(m_base + i * 16 + lr) * HPITCH + ks * 32 + lq * 8];
            #pragma unroll
            for (int j = 0; j < 4; ++j)
                bfr[j] = *(const bf16x8*)(wbase + (size_t)j * 16 * HH + ks * 32);
            #pragma unroll
            for (int i = 0; i < 2; ++i)
                #pragma unroll
                for (int j = 0; j < 4; ++j)
                    acc[i][j] = __builtin_amdgcn_mfma_f32_16x16x32_bf16(af[i], bfr[j], acc[i][j], 0, 0, 0);
        }

        __syncthreads();   // K-loop reads of sh_h complete before reuse as fp32 tile
        float* tile = (float*)sh_h;   // 128 x TPITCH fp32 (66560 B <= 67584 B)
        #pragma unroll
        for (int j = 0; j < 4; ++j) {
            const int n = n_base + j * 16 + lr;
            #pragma unroll
            for (int i = 0; i < 2; ++i) {
                #pragma unroll
                for (int r = 0; r < 4; ++r)
                    tile[(m_base + i * 16 + lq * 4 + r) * TPITCH + n] = acc[i][j][r];
            }
        }
        __syncthreads();

        // segmented reduction: sorted dst -> ~1 atomic per segment per col
        {
            const int col = tid & 127;
            const int r0  = (tid >> 7) * 32;       // 4 chunks of 32 rows
            int cur = s_dst[r0];
            float run = 0.f;
            #pragma unroll 1
            for (int r = r0; r < r0 + 32; ++r) {
                const int d = s_dst[r];            // wave-uniform
                if (d != cur) {
                    atomicAdd(&outp[(size_t)cur * FF + col], run);
                    run = 0.f; cur = d;
                }
                run += tile[r * TPITCH + col];
            }
            atomicAdd(&outp[(size_t)cur * FF + col], run);
        }
    }
}

__global__ __launch_bounds__(256) void finalize_kernel(const int* __restrict__ cnt,
                                                       const float* __restrict__ b3,
                                                       float* __restrict__ out)
{
    const int i4 = blockIdx.x * 256 + threadIdx.x;
    if (i4 < OUT_VEC) {
        const int node = i4 >> 5;               // 32 float4 per row
        const int cb   = (i4 & 31) * 4;
        const int c_i  = cnt[node];
        float4 v = ((float4*)out)[i4];
        if (c_i > 0) {
            const float inv = 1.0f / (float)c_i;
            v.x = tanhf(v.x * inv + b3[cb + 0]);
            v.y = tanhf(v.y * inv + b3[cb + 1]);
            v.z = tanhf(v.z * inv + b3[cb + 2]);
            v.w = tanhf(v.w * inv + b3[cb + 3]);
        } else {
            v = (float4){0.f, 0.f, 0.f, 0.f};   // reference: tanh(0/1) = 0
        }
        ((float4*)out)[i4] = v;
    }
}

extern "C" void kernel_launch(void* const* d_in, const int* in_sizes, int n_in,
                              void* d_out, int out_size, void* d_ws, size_t ws_size,
                              hipStream_t stream)
{
    const float* x   = (const float*)d_in[0];
    const int*   ei  = (const int*)d_in[1];
    const float* W1  = (const float*)d_in[2];
    const float* b1  = (const float*)d_in[3];
    const float* g1  = (const float*)d_in[4];
    const float* be1 = (const float*)d_in[5];
    const float* rm1 = (const float*)d_in[6];
    const float* rv1 = (const float*)d_in[7];
    const float* W2  = (const float*)d_in[8];
    const float* b2  = (const float*)d_in[9];
    const float* g2  = (const float*)d_in[10];
    const float* be2 = (const float*)d_in[11];
    const float* rm2 = (const float*)d_in[12];
    const float* rv2 = (const float*)d_in[13];
    const float* W3  = (const float*)d_in[14];
    const float* b3  = (const float*)d_in[15];

    char* ws = (char*)d_ws;
    int* cnt_i = (int*)(ws + CNT_OFF);
    int* wptr  = (int*)(ws + WPTR_OFF);
    unsigned short* ssrc = (unsigned short*)(ws + SSRC_OFF);
    unsigned short* sdst = (unsigned short*)(ws + SDST_OFF);
    __bf16* xb  = (__bf16*)(ws + XB_OFF);
    __bf16* w1b = (__bf16*)(ws + W1B_OFF);
    __bf16* w2b = (__bf16*)(ws + W2B_OFF);
    __bf16* w3b = (__bf16*)(ws + W3B_OFF);
    float* outp = (float*)d_out;

    hipMemsetAsync(cnt_i, 0, NN * sizeof(int), stream);
    prep_kernel<<<(CVT_VEC + 255) / 256, 256, 0, stream>>>(x, W1, W2, W3, ei,
                                                           xb, w1b, w2b, w3b,
                                                           cnt_i, outp);
    scan_kernel<<<1, 1024, 0, stream>>>(cnt_i, wptr);
    scatter_kernel<<<(EE + 255) / 256, 256, 0, stream>>>(ei, wptr, ssrc, sdst);
    fused_edge_mlp<<<EE / MT, NTHREADS, 0, stream>>>(xb, ssrc, sdst,
                                                     w1b, b1, g1, be1, rm1, rv1,
                                                     w2b, b2, g2, be2, rm2, rv2,
                                                     w3b, outp);
    finalize_kernel<<<(OUT_VEC + 255) / 256, 256, 0, stream>>>(cnt_i, b3, outp);
}

// Round 8
// 389.789 us; speedup vs baseline: 1.9110x; 1.0050x over previous
//
#include <hip/hip_runtime.h>
#include <math.h>

#define NN 20000
#define EE 320000
#define FF 128
#define HH 256
#define HPITCH 264   // 256 + 8 bf16 pad
#define TPITCH 130   // fp32 epilogue tile pitch
#define MT 128       // edges per block
#define NTHREADS 512

typedef __bf16 bf16x8 __attribute__((ext_vector_type(8)));
typedef float  f32x4  __attribute__((ext_vector_type(4)));

// ---- workspace layout (bytes) ----
#define CNT_OFF   0          // NN int32 (memset to 0)
#define WPTR_OFF  80000      // NN int32
#define SSRC_OFF  160000     // EE u16
#define SDST_OFF  800000     // EE u16
#define XB_OFF    1440000    // NN*FF bf16
#define W1B_OFF   6560000    // HH*HH bf16
#define W2B_OFF   6691072    // HH*HH bf16
#define W3B_OFF   6822144    // FF*HH bf16  (end 6,887,680)

#define CVT_VEC ((NN*FF + HH*HH + HH*HH + FF*HH) / 4)   // 680,960 float4 groups
#define OUT_VEC (NN * FF / 4)                           // 640,000 float4

// zero d_out + convert x/W1/W2/W3 to bf16 + dst histogram, one dispatch
__global__ __launch_bounds__(256) void prep_kernel(
    const float* __restrict__ x,  const float* __restrict__ W1,
    const float* __restrict__ W2, const float* __restrict__ W3,
    const int*   __restrict__ eidx,
    __bf16* __restrict__ xb, __bf16* __restrict__ w1b,
    __bf16* __restrict__ w2b, __bf16* __restrict__ w3b,
    int* __restrict__ cnt, float* __restrict__ outp)
{
    const int gid = blockIdx.x * 256 + threadIdx.x;
    if (gid < OUT_VEC) ((float4*)outp)[gid] = (float4){0.f, 0.f, 0.f, 0.f};
    if (gid < CVT_VEC) {
        const size_t base = (size_t)gid * 4;
        const float* src; __bf16* dst; size_t off;
        if (base < (size_t)NN * FF)              { src = x;  dst = xb;  off = base; }
        else if (base < (size_t)NN*FF + HH*HH)   { src = W1; dst = w1b; off = base - (size_t)NN*FF; }
        else if (base < (size_t)NN*FF + 2*HH*HH) { src = W2; dst = w2b; off = base - (size_t)NN*FF - HH*HH; }
        else                                     { src = W3; dst = w3b; off = base - (size_t)NN*FF - 2*HH*HH; }
        float4 v = *(const float4*)(src + off);
        __bf16 o[4] = { (__bf16)v.x, (__bf16)v.y, (__bf16)v.z, (__bf16)v.w };
        __builtin_memcpy(dst + off, o, 8);
    }
    if (gid < EE) atomicAdd(&cnt[eidx[EE + gid]], 1);
}

// exclusive prefix sum of cnt[0..NN) -> wptr, single block of 1024 threads
__global__ __launch_bounds__(1024) void scan_kernel(const int* __restrict__ cnt,
                                                    int* __restrict__ wptr)
{
    __shared__ int s_part[1024];
    const int t = threadIdx.x;
    const int base = t * 20;
    int loc[20];
    int sum = 0;
    #pragma unroll
    for (int i = 0; i < 20; ++i) {
        const int idx = base + i;
        const int v = (idx < NN) ? cnt[idx] : 0;
        loc[i] = sum;
        sum += v;
    }
    s_part[t] = sum;
    __syncthreads();
    for (int d = 1; d < 1024; d <<= 1) {
        const int v = (t >= d) ? s_part[t - d] : 0;
        __syncthreads();
        s_part[t] += v;
        __syncthreads();
    }
    const int excl = s_part[t] - sum;
    #pragma unroll
    for (int i = 0; i < 20; ++i) {
        const int idx = base + i;
        if (idx < NN) wptr[idx] = excl + loc[i];
    }
}

__global__ __launch_bounds__(256) void scatter_kernel(const int* __restrict__ eidx,
                                                      int* __restrict__ wptr,
                                                      unsigned short* __restrict__ ssrc,
                                                      unsigned short* __restrict__ sdst)
{
    const int e = blockIdx.x * 256 + threadIdx.x;
    if (e < EE) {
        const int d = eidx[EE + e];
        const int pos = atomicAdd(&wptr[d], 1);
        ssrc[pos] = (unsigned short)eidx[e];
        sdst[pos] = (unsigned short)d;
    }
}

__global__ __launch_bounds__(NTHREADS, 2) void fused_edge_mlp(
    const __bf16* __restrict__ x,
    const unsigned short* __restrict__ ssrc,
    const unsigned short* __restrict__ sdst,
    const __bf16* __restrict__ W1,
    const float*  __restrict__ b1, const float* __restrict__ g1,
    const float*  __restrict__ be1, const float* __restrict__ rm1,
    const float*  __restrict__ rv1,
    const __bf16* __restrict__ W2,
    const float*  __restrict__ b2, const float* __restrict__ g2,
    const float*  __restrict__ be2, const float* __restrict__ rm2,
    const float*  __restrict__ rv2,
    const __bf16* __restrict__ W3,
    float* __restrict__ outp)
{
    __shared__ __align__(16) __bf16 sh_h[MT * HPITCH];   // 67584 B (reused as fp32 128x130 tile)
    __shared__ float s_scale[2][HH];
    __shared__ float s_c[2][HH];
    __shared__ int   s_dst[MT];
    __shared__ int   s_src[MT];

    const int tid = threadIdx.x;
    const int e0  = blockIdx.x * MT;

    if (tid < MT) {
        s_src[tid] = (int)ssrc[e0 + tid];
        s_dst[tid] = (int)sdst[e0 + tid];
    }
    if (tid < HH) {
        float sc1 = g1[tid] * rsqrtf(rv1[tid] + 1e-5f);
        s_scale[0][tid] = sc1;
        s_c[0][tid] = (b1[tid] - rm1[tid]) * sc1 + be1[tid];
        float sc2 = g2[tid] * rsqrtf(rv2[tid] + 1e-5f);
        s_scale[1][tid] = sc2;
        s_c[1][tid] = (b2[tid] - rm2[tid]) * sc2 + be2[tid];
    }
    __syncthreads();

    // ---- gather & concat: sh_h[r][0:128] = x[dst], sh_h[r][128:256] = x[src]-x[dst]
    {
        const int r = tid >> 2;       // 0..127
        const int q = tid & 3;        // 32-col quarter
        const __bf16* xd = x + (size_t)s_dst[r] * FF + q * 32;
        const __bf16* xs = x + (size_t)s_src[r] * FF + q * 32;
        uint4 di[4], sj[4];
        #pragma unroll
        for (int i = 0; i < 4; ++i) { di[i] = ((const uint4*)xd)[i]; sj[i] = ((const uint4*)xs)[i]; }
        __bf16* hrow = &sh_h[r * HPITCH];
        #pragma unroll
        for (int i = 0; i < 4; ++i) ((uint4*)&hrow[q * 32])[i] = di[i];
        #pragma unroll
        for (int i = 0; i < 4; ++i) {
            __bf16 a[8], b[8], ov[8];
            __builtin_memcpy(a, &di[i], 16);
            __builtin_memcpy(b, &sj[i], 16);
            #pragma unroll
            for (int j = 0; j < 8; ++j) ov[j] = (__bf16)((float)b[j] - (float)a[j]);
            uint4 o;
            __builtin_memcpy(&o, ov, 16);
            ((uint4*)&hrow[128 + q * 32])[i] = o;
        }
    }
    __syncthreads();

    const int w    = tid >> 6;
    const int lane = tid & 63;
    const int lr   = lane & 15;
    const int lq   = lane >> 4;

    // ---- stages 1 & 2: h = relu(scale * (h @ W^T) + c), in-place in sh_h
    // B held in registers per K-half (64 VGPRs); inner loop = ds_read + MFMA only.
    #pragma unroll 1
    for (int stage = 0; stage < 2; ++stage) {
        const __bf16* Wp = (stage == 0) ? W1 : W2;
        const int wm = w >> 2, wn = w & 3;          // 2 x 4 wave grid
        const int m_base = wm * 64, n_base = wn * 64;
        const __bf16* wbase = Wp + (size_t)(n_base + lr) * HH + lq * 8;
        f32x4 acc[4][4];
        #pragma unroll
        for (int i = 0; i < 4; ++i)
            #pragma unroll
            for (int j = 0; j < 4; ++j) acc[i][j] = (f32x4){0.f, 0.f, 0.f, 0.f};

        #pragma unroll 1
        for (int kh = 0; kh < 2; ++kh) {            // two K-halves of 128
            bf16x8 breg[4][4];
            #pragma unroll
            for (int ks = 0; ks < 4; ++ks)
                #pragma unroll
                for (int j = 0; j < 4; ++j)
                    breg[ks][j] = *(const bf16x8*)(wbase + (size_t)j * 16 * HH + kh * 128 + ks * 32);
            #pragma unroll
            for (int ks = 0; ks < 4; ++ks) {
                bf16x8 af[4];
                #pragma unroll
                for (int i = 0; i < 4; ++i)
                    af[i] = *(const bf16x8*)&sh_h[(m_base + i * 16 + lr) * HPITCH + kh * 128 + ks * 32 + lq * 8];
                #pragma unroll
                for (int i = 0; i < 4; ++i)
                    #pragma unroll
                    for (int j = 0; j < 4; ++j)
                        acc[i][j] = __builtin_amdgcn_mfma_f32_16x16x32_bf16(af[i], breg[ks][j], acc[i][j], 0, 0, 0);
            }
        }
        __syncthreads();   // all reads of sh_h done -> safe to overwrite in place
        #pragma unroll
        for (int j = 0; j < 4; ++j) {
            const int n = n_base + j * 16 + lr;
            const float sc = s_scale[stage][n];
            const float cc = s_c[stage][n];
            #pragma unroll
            for (int i = 0; i < 4; ++i) {
                #pragma unroll
                for (int r = 0; r < 4; ++r) {
                    const int m = m_base + i * 16 + lq * 4 + r;
                    float v = acc[i][j][r] * sc + cc;
                    sh_h[m * HPITCH + n] = (__bf16)fmaxf(v, 0.0f);
                }
            }
        }
        __syncthreads();   // writes visible before next stage reads
    }

    // ---- stage 3: [128x256] @ W3^T -> [128x128], LDS tile, segmented scatter-add
    {
        const int wm = w >> 1, wn = w & 1;          // 4 x 2 wave grid
        const int m_base = wm * 32, n_base = wn * 64;
        const __bf16* wbase = W3 + (size_t)(n_base + lr) * HH + lq * 8;
        f32x4 acc[2][4];
        #pragma unroll
        for (int i = 0; i < 2; ++i)
            #pragma unroll
            for (int j = 0; j < 4; ++j) acc[i][j] = (f32x4){0.f, 0.f, 0.f, 0.f};

        #pragma unroll 1
        for (int kh = 0; kh < 2; ++kh) {
            bf16x8 breg[4][4];
            #pragma unroll
            for (int ks = 0; ks < 4; ++ks)
                #pragma unroll
                for (int j = 0; j < 4; ++j)
                    breg[ks][j] = *(const bf16x8*)(wbase + (size_t)j * 16 * HH + kh * 128 + ks * 32);
            #pragma unroll
            for (int ks = 0; ks < 4; ++ks) {
                bf16x8 af[2];
                #pragma unroll
                for (int i = 0; i < 2; ++i)
                    af[i] = *(const bf16x8*)&sh_h[(m_base + i * 16 + lr) * HPITCH + kh * 128 + ks * 32 + lq * 8];
                #pragma unroll
                for (int i = 0; i < 2; ++i)
                    #pragma unroll
                    for (int j = 0; j < 4; ++j)
                        acc[i][j] = __builtin_amdgcn_mfma_f32_16x16x32_bf16(af[i], breg[ks][j], acc[i][j], 0, 0, 0);
            }
        }

        __syncthreads();   // K-loop reads of sh_h complete before reuse as fp32 tile
        float* tile = (float*)sh_h;   // 128 x TPITCH fp32 (66560 B <= 67584 B)
        #pragma unroll
        for (int j = 0; j < 4; ++j) {
            const int n = n_base + j * 16 + lr;
            #pragma unroll
            for (int i = 0; i < 2; ++i) {
                #pragma unroll
                for (int r = 0; r < 4; ++r)
                    tile[(m_base + i * 16 + lq * 4 + r) * TPITCH + n] = acc[i][j][r];
            }
        }
        __syncthreads();

        // segmented reduction: sorted dst -> ~1 atomic per segment per col
        {
            const int col = tid & 127;
            const int r0  = (tid >> 7) * 32;       // 4 chunks of 32 rows
            int cur = s_dst[r0];
            float run = 0.f;
            #pragma unroll 1
            for (int r = r0; r < r0 + 32; ++r) {
                const int d = s_dst[r];            // wave-uniform
                if (d != cur) {
                    atomicAdd(&outp[(size_t)cur * FF + col], run);
                    run = 0.f; cur = d;
                }
                run += tile[r * TPITCH + col];
            }
            atomicAdd(&outp[(size_t)cur * FF + col], run);
        }
    }
}

__global__ __launch_bounds__(256) void finalize_kernel(const int* __restrict__ cnt,
                                                       const float* __restrict__ b3,
                                                       float* __restrict__ out)
{
    const int i4 = blockIdx.x * 256 + threadIdx.x;
    if (i4 < OUT_VEC) {
        const int node = i4 >> 5;               // 32 float4 per row
        const int cb   = (i4 & 31) * 4;
        const int c_i  = cnt[node];
        float4 v = ((float4*)out)[i4];
        if (c_i > 0) {
            const float inv = 1.0f / (float)c_i;
            v.x = tanhf(v.x * inv + b3[cb + 0]);
            v.y = tanhf(v.y * inv + b3[cb + 1]);
            v.z = tanhf(v.z * inv + b3[cb + 2]);
            v.w = tanhf(v.w * inv + b3[cb + 3]);
        } else {
            v = (float4){0.f, 0.f, 0.f, 0.f};   // reference: tanh(0/1) = 0
        }
        ((float4*)out)[i4] = v;
    }
}

extern "C" void kernel_launch(void* const* d_in, const int* in_sizes, int n_in,
                              void* d_out, int out_size, void* d_ws, size_t ws_size,
                              hipStream_t stream)
{
    const float* x   = (const float*)d_in[0];
    const int*   ei  = (const int*)d_in[1];
    const float* W1  = (const float*)d_in[2];
    const float* b1  = (const float*)d_in[3];
    const float* g1  = (const float*)d_in[4];
    const float* be1 = (const float*)d_in[5];
    const float* rm1 = (const float*)d_in[6];
    const float* rv1 = (const float*)d_in[7];
    const float* W2  = (const float*)d_in[8];
    const float* b2  = (const float*)d_in[9];
    const float* g2  = (const float*)d_in[10];
    const float* be2 = (const float*)d_in[11];
    const float* rm2 = (const float*)d_in[12];
    const float* rv2 = (const float*)d_in[13];
    const float* W3  = (const float*)d_in[14];
    const float* b3  = (const float*)d_in[15];

    char* ws = (char*)d_ws;
    int* cnt_i = (int*)(ws + CNT_OFF);
    int* wptr  = (int*)(ws + WPTR_OFF);
    unsigned short* ssrc = (unsigned short*)(ws + SSRC_OFF);
    unsigned short* sdst = (unsigned short*)(ws + SDST_OFF);
    __bf16* xb  = (__bf16*)(ws + XB_OFF);
    __bf16* w1b = (__bf16*)(ws + W1B_OFF);
    __bf16* w2b = (__bf16*)(ws + W2B_OFF);
    __bf16* w3b = (__bf16*)(ws + W3B_OFF);
    float* outp = (float*)d_out;

    hipMemsetAsync(cnt_i, 0, NN * sizeof(int), stream);
    prep_kernel<<<(CVT_VEC + 255) / 256, 256, 0, stream>>>(x, W1, W2, W3, ei,
                                                           xb, w1b, w2b, w3b,
                                                           cnt_i, outp);
    scan_kernel<<<1, 1024, 0, stream>>>(cnt_i, wptr);
    scatter_kernel<<<(EE + 255) / 256, 256, 0, stream>>>(ei, wptr, ssrc, sdst);
    fused_edge_mlp<<<EE / MT, NTHREADS, 0, stream>>>(xb, ssrc, sdst,
                                                     w1b, b1, g1, be1, rm1, rv1,
                                                     w2b, b2, g2, be2, rm2, rv2,
                                                     w3b, outp);
    finalize_kernel<<<(OUT_VEC + 255) / 256, 256, 0, stream>>>(cnt_i, b3, outp);
}